// Round 7
// baseline (212.571 us; speedup 1.0000x reference)
//
#include <hip/hip_runtime.h>

// NIGnet: X -> 64x [Y = X@W.T + b; X = (tanh(Y)+Y)/2] -> X@fW.T -> L2 normalize.
// Calibration (R1-R6): three different schedules all give 35 cyc per wave64-value
// (5 full-rate + 1 exp + 1 rcp) with VALUBusy ~82% => trans ops are ~12.5 cyc/wave64
// ISSUE (1/6 rate), full-rate 2 cyc, and we were AT the issue roofline, zero stall.
// R7 cuts trans count: 8-way batched reciprocal. d_i = exp2(min(y_i,13.3)) + 1
// is in (1, 1.01e4]; product of 8 <= 1.1e32 (no overflow); one v_rcp of the full
// product + prefix/suffix muls reconstructs all 8 reciprocals.
// Per 8 values: 69 full-rate + 9 trans = 31.3 cyc/value vs 35 (-10.5%).
// Clamp only feeds exp (true y still used in the residual): tanh err <= 2e-4,
// and only where tanh' ~ 0 — way inside the 1.87e-2 threshold.

#define KPT 8          // points per thread = 2 groups of 4 points (8 values each)
#define BLOCK 256

__global__ __launch_bounds__(BLOCK, 4) void nig_kernel(
    const float* __restrict__ X_in,
    const float* __restrict__ Ws,    // [L,2,2] row-major
    const float* __restrict__ bs,    // [L,2]
    const float* __restrict__ fW,    // [2,2]
    float* __restrict__ out,
    int M,                           // float4 chunks = N/2
    int L)
{
    const int tid = blockIdx.x * blockDim.x + threadIdx.x;
    const int nthreads = gridDim.x * blockDim.x;
    const float4* __restrict__ in4 = (const float4*)X_in;
    float4* __restrict__ out4 = (float4*)out;

    const float C     = 2.8853900817779268f;   // 2*log2(e)
    const float halfC = 1.4426950408889634f;   // C/2
    const float YCLMP = 13.3f;                 // exp2(13.3) ~ 1.01e4

    // State scaled by C: u = C*x; y_u = W@u + C*b; exp2(y_u) = exp(2*y).
    // Final L2-normalize cancels the uniform scale.
    float u0[KPT], u1[KPT];
    int idx[KPT / 2]; bool ok[KPT / 2];
    #pragma unroll
    for (int j = 0; j < KPT / 2; ++j) {
        idx[j] = tid + j * nthreads;
        ok[j] = idx[j] < M;
        float4 v = ok[j] ? in4[idx[j]] : make_float4(0.f, 0.f, 0.f, 0.f);
        u0[2 * j]     = v.x * C; u1[2 * j]     = v.y * C;
        u0[2 * j + 1] = v.z * C; u1[2 * j + 1] = v.w * C;
    }

    float4 w = ((const float4*)Ws)[0];
    float2 b = ((const float2*)bs)[0];

    for (int l = 0; l < L; ++l) {
        const int ln = (l + 1 < L) ? (l + 1) : l;
        float4 wn = ((const float4*)Ws)[ln];   // prefetch next layer (s_load)
        float2 bn = ((const float2*)bs)[ln];

        const float cb0 = C * b.x;
        const float cb1 = C * b.y;

        #pragma unroll
        for (int g = 0; g < KPT / 4; ++g) {
            float y0[4], y1[4], d0[4], d1[4];
            #pragma unroll
            for (int p = 0; p < 4; ++p) {
                const int k = g * 4 + p;
                y0[p] = fmaf(w.x, u0[k], fmaf(w.y, u1[k], cb0));
                y1[p] = fmaf(w.z, u0[k], fmaf(w.w, u1[k], cb1));
                d0[p] = __builtin_amdgcn_exp2f(fminf(y0[p], YCLMP)) + 1.0f;
                d1[p] = __builtin_amdgcn_exp2f(fminf(y1[p], YCLMP)) + 1.0f;
            }
            // Product tree over the 8 d's.
            float pA = d0[0] * d1[0];
            float pB = d0[1] * d1[1];
            float pC = d0[2] * d1[2];
            float pD = d0[3] * d1[3];
            float qAB = pA * pB, qCD = pC * pD;
            float R = __builtin_amdgcn_rcpf(qAB * qCD);
            // Reconstruct per-value reciprocals: r = 1/d_i.
            float iAB = R * qCD;       // 1/qAB
            float iCD = R * qAB;       // 1/qCD
            float iA = iAB * pB;       // 1/pA
            float iB = iAB * pA;
            float iC = iCD * pD;
            float iD = iCD * pC;
            float r00 = iA * d1[0], r10 = iA * d0[0];
            float r01 = iB * d1[1], r11 = iB * d0[1];
            float r02 = iC * d1[2], r12 = iC * d0[2];
            float r03 = iD * d1[3], r13 = iD * d0[3];
            // u' = 0.5*y + C*(0.5 - r)  (tanh = 1 - 2r); true y, not clamped.
            u0[g * 4 + 0] = fmaf(-C, r00, fmaf(0.5f, y0[0], halfC));
            u1[g * 4 + 0] = fmaf(-C, r10, fmaf(0.5f, y1[0], halfC));
            u0[g * 4 + 1] = fmaf(-C, r01, fmaf(0.5f, y0[1], halfC));
            u1[g * 4 + 1] = fmaf(-C, r11, fmaf(0.5f, y1[1], halfC));
            u0[g * 4 + 2] = fmaf(-C, r02, fmaf(0.5f, y0[2], halfC));
            u1[g * 4 + 2] = fmaf(-C, r12, fmaf(0.5f, y1[2], halfC));
            u0[g * 4 + 3] = fmaf(-C, r03, fmaf(0.5f, y0[3], halfC));
            u1[g * 4 + 3] = fmaf(-C, r13, fmaf(0.5f, y1[3], halfC));
        }
        w = wn; b = bn;
    }

    // Final linear + L2 normalize (uniform scale C cancels).
    const float g0 = fW[0], g1 = fW[1], g2 = fW[2], g3 = fW[3];

    #pragma unroll
    for (int j = 0; j < KPT / 2; ++j) {
        if (!ok[j]) continue;
        float4 o;
        #pragma unroll
        for (int h = 0; h < 2; ++h) {
            const int k = 2 * j + h;
            float z0 = fmaf(g0, u0[k], g1 * u1[k]);
            float z1 = fmaf(g2, u0[k], g3 * u1[k]);
            float s  = fmaf(z0, z0, z1 * z1);
            float n  = __builtin_amdgcn_sqrtf(s);
            float iv = __builtin_amdgcn_rcpf(fmaxf(n, 1e-12f));
            if (h == 0) { o.x = z0 * iv; o.y = z1 * iv; }
            else        { o.z = z0 * iv; o.w = z1 * iv; }
        }
        out4[idx[j]] = o;
    }
}

extern "C" void kernel_launch(void* const* d_in, const int* in_sizes, int n_in,
                              void* d_out, int out_size, void* d_ws, size_t ws_size,
                              hipStream_t stream) {
    // 0=T(unused), 1=closed_manifold [N,2], 2=Ws [L,2,2], 3=bs [L,2], 4=final_W [2,2]
    const float* X  = (const float*)d_in[1];
    const float* Ws = (const float*)d_in[2];
    const float* bs = (const float*)d_in[3];
    const float* fW = (const float*)d_in[4];
    float* out = (float*)d_out;

    const int L = in_sizes[2] / 4;
    const int M = in_sizes[1] / 4;
    const int threads = (M + (KPT / 2) - 1) / (KPT / 2);
    const int grid = (threads + BLOCK - 1) / BLOCK;

    nig_kernel<<<grid, BLOCK, 0, stream>>>(X, Ws, bs, fW, out, M, L);
}

// Round 8
// 191.121 us; speedup vs baseline: 1.1122x; 1.1122x over previous
//
#include <hip/hip_runtime.h>

// NIGnet: X -> 64x [Y = X@W.T + b; X = (tanh(Y)+Y)/2] -> X@fW.T -> L2 normalize.
// Empirical law (R1/R4/R5/R7): duration tracks TOTAL VALU instruction count
// (~5 cyc/instr at SIMD level); exp/rcp cost ~ fma; batching rcp regressed.
// R8: 6-instruction inner loop (was 7). State s = 2C*x, weights halved,
// residual's +C folded into bias:
//   Y+  = (W/2)@s + C*(b+1)                  (2 fma)
//   E   = exp2(Y+)                           (1 trans)   e^{2y} = k*E, k = e^-2
//   d   = fma(k, E, 1)                       (1 fma — replaces the old +1 add)
//   r   = rcp(d)                             (1 trans)   r = 1/(e^{2y}+1)
//   s'  = fma(-2C, r, Y+)                    (1 fma — whole residual update)
// Saturation exact: E->inf => r=0 => s'=Y+ ((y+1)/2 scaled); E->0 => r=1 => (y-1)/2.
// Final L2-normalize cancels the uniform 2C scale (no un-scale needed).

#define KPT 8          // points per thread (4 float4 chunks)
#define BLOCK 256

__global__ __launch_bounds__(BLOCK, 8) void nig_kernel(
    const float* __restrict__ X_in,
    const float* __restrict__ Ws,    // [L,2,2] row-major
    const float* __restrict__ bs,    // [L,2]
    const float* __restrict__ fW,    // [2,2]
    float* __restrict__ out,
    int M,                           // float4 chunks = N/2
    int L)
{
    const int tid = blockIdx.x * blockDim.x + threadIdx.x;
    const int nthreads = gridDim.x * blockDim.x;
    const float4* __restrict__ in4 = (const float4*)X_in;
    float4* __restrict__ out4 = (float4*)out;

    const float C    = 2.8853900817779268f;    // 2*log2(e)
    const float twoC = 5.7707801635558537f;    // 2C
    const float n2C  = -5.7707801635558537f;   // -2C
    const float kE   = 0.13533528323661270f;   // 2^-C = e^-2

    // State s = 2C * x.
    float s0[KPT], s1[KPT];
    int idx[KPT / 2]; bool ok[KPT / 2];
    #pragma unroll
    for (int j = 0; j < KPT / 2; ++j) {
        idx[j] = tid + j * nthreads;
        ok[j] = idx[j] < M;
        float4 v = ok[j] ? in4[idx[j]] : make_float4(0.f, 0.f, 0.f, 0.f);
        s0[2 * j]     = v.x * twoC; s1[2 * j]     = v.y * twoC;
        s0[2 * j + 1] = v.z * twoC; s1[2 * j + 1] = v.w * twoC;
    }

    float4 w = ((const float4*)Ws)[0];
    float2 b = ((const float2*)bs)[0];

    for (int l = 0; l < L; ++l) {
        const int ln = (l + 1 < L) ? (l + 1) : l;
        float4 wn = ((const float4*)Ws)[ln];   // prefetch next layer (s_load)
        float2 bn = ((const float2*)bs)[ln];

        // Uniform per-layer transforms (6 VALU ops amortized over 16 values).
        const float hx = 0.5f * w.x, hy = 0.5f * w.y;
        const float hz = 0.5f * w.z, hw = 0.5f * w.w;
        const float cb0 = C * (b.x + 1.0f);    // C*b + C (residual's +C folded in)
        const float cb1 = C * (b.y + 1.0f);

        #pragma unroll
        for (int k = 0; k < KPT; ++k) {
            float Yp0 = fmaf(hx, s0[k], fmaf(hy, s1[k], cb0));
            float Yp1 = fmaf(hz, s0[k], fmaf(hw, s1[k], cb1));
            float E0 = __builtin_amdgcn_exp2f(Yp0);
            float E1 = __builtin_amdgcn_exp2f(Yp1);
            float d0 = fmaf(kE, E0, 1.0f);     // e^{2y} + 1
            float d1 = fmaf(kE, E1, 1.0f);
            float r0 = __builtin_amdgcn_rcpf(d0);
            float r1 = __builtin_amdgcn_rcpf(d1);
            s0[k] = fmaf(n2C, r0, Yp0);        // s' = Y+ - 2C*r
            s1[k] = fmaf(n2C, r1, Yp1);
        }
        w = wn; b = bn;
    }

    // Final linear + L2 normalize (uniform scale 2C cancels).
    const float g0 = fW[0], g1 = fW[1], g2 = fW[2], g3 = fW[3];

    #pragma unroll
    for (int j = 0; j < KPT / 2; ++j) {
        if (!ok[j]) continue;
        float4 o;
        #pragma unroll
        for (int h = 0; h < 2; ++h) {
            const int k = 2 * j + h;
            float z0 = fmaf(g0, s0[k], g1 * s1[k]);
            float z1 = fmaf(g2, s0[k], g3 * s1[k]);
            float s  = fmaf(z0, z0, z1 * z1);
            float n  = __builtin_amdgcn_sqrtf(s);
            float iv = __builtin_amdgcn_rcpf(fmaxf(n, 1e-12f));
            if (h == 0) { o.x = z0 * iv; o.y = z1 * iv; }
            else        { o.z = z0 * iv; o.w = z1 * iv; }
        }
        out4[idx[j]] = o;
    }
}

extern "C" void kernel_launch(void* const* d_in, const int* in_sizes, int n_in,
                              void* d_out, int out_size, void* d_ws, size_t ws_size,
                              hipStream_t stream) {
    // 0=T(unused), 1=closed_manifold [N,2], 2=Ws [L,2,2], 3=bs [L,2], 4=final_W [2,2]
    const float* X  = (const float*)d_in[1];
    const float* Ws = (const float*)d_in[2];
    const float* bs = (const float*)d_in[3];
    const float* fW = (const float*)d_in[4];
    float* out = (float*)d_out;

    const int L = in_sizes[2] / 4;
    const int M = in_sizes[1] / 4;
    const int threads = (M + (KPT / 2) - 1) / (KPT / 2);
    const int grid = (threads + BLOCK - 1) / BLOCK;

    nig_kernel<<<grid, BLOCK, 0, stream>>>(X, Ws, bs, fW, out, M, L);
}